// Round 3
// baseline (796.926 us; speedup 1.0000x reference)
//
#include <hip/hip_runtime.h>
#include <hip/hip_bf16.h>
#include <type_traits>

// Sizes (fixed by the problem)
// B=4, S=4096, H=1024, NH=8, HD=128, L=64 ; d = NH*HD = 1024
// M = B*S = 16384 rows, K = N = 1024 for all five GEMMs.
#define GATE_ELEMS 16777216ull   // 16384 * 1024

typedef float f32x4 __attribute__((ext_vector_type(4)));
typedef short s16x8 __attribute__((ext_vector_type(8)));

__device__ __forceinline__ unsigned short f2bf(float f) {
  union { float f; unsigned u; } v; v.f = f;
  unsigned r = v.u + 0x7fffu + ((v.u >> 16) & 1u);   // RNE round to bf16
  return (unsigned short)(r >> 16);
}

__device__ __forceinline__ float bf2f(unsigned short u) {
  union { unsigned u; float f; } v; v.u = ((unsigned)u) << 16;
  return v.f;
}

__device__ __forceinline__ float sigmoidf_(float x) {
  return 1.0f / (1.0f + __expf(-x));
}

__device__ __forceinline__ float tanhf_(float x) {
  // clamped to keep __expf finite; tanh saturates well before |x|=15
  x = fminf(fmaxf(x, -15.f), 15.f);
  const float e = __expf(2.f * x);
  return (e - 1.f) / (e + 1.f);
}

// ---------------------------------------------------------------------------
// GEMM: C[m,n] = sum_k A[m,k] * B[n,k] + bias[n]
// A: M x K row-major, fp32 (converted to bf16 on the fly) or bf16 (ushort)
// B: N x K row-major fp32 weights (converted on the fly)
// C: fp32 or bf16 (ushort) per OT
// Tile: 128x128, BK=32, 4 waves (2x2), each wave 64x64 via 4x4 16x16x32 MFMAs.
// LDS rows padded to 40 bf16 (80 B) -> fragment ds_read_b128 is 2-way (free).
// ---------------------------------------------------------------------------
template <typename AT, typename OT>
__global__ __launch_bounds__(256, 3)
void gemm_bt_kernel(const AT* __restrict__ A, const float* __restrict__ B,
                    const float* __restrict__ bias, OT* __restrict__ C,
                    int M, int N, int K) {
  __shared__ unsigned short As[128 * 40];
  __shared__ unsigned short Bs[128 * 40];
  const int tid  = threadIdx.x;
  const int lane = tid & 63;
  const int wave = tid >> 6;
  const int wr = wave >> 1;          // wave row (0..1) -> 64-row slab
  const int wc = wave & 1;           // wave col (0..1) -> 64-col slab
  const int m0 = blockIdx.y * 128;
  const int n0 = blockIdx.x * 128;

  f32x4 acc[4][4];
#pragma unroll
  for (int i = 0; i < 4; ++i)
#pragma unroll
    for (int j = 0; j < 4; ++j)
      acc[i][j] = (f32x4){0.f, 0.f, 0.f, 0.f};

  const int frow = lane & 15;        // fragment row (A) / col (B)
  const int kq   = lane >> 4;        // 0..3 -> k-quadrant
  const int krow = kq * 8;           // k offset of this lane's 8 elems

  for (int kt = 0; kt < K; kt += 32) {
    // ---- stage A tile ----
    if constexpr (std::is_same<AT, float>::value) {
#pragma unroll
      for (int i = 0; i < 4; ++i) {
        const int fi  = (i * 256 + tid) * 4;  // flat float index in 128x32 tile
        const int row = fi >> 5;
        const int col = fi & 31;
        const float4 av = *reinterpret_cast<const float4*>(A + (size_t)(m0 + row) * K + kt + col);
        *reinterpret_cast<ushort4*>(&As[row * 40 + col]) =
            make_ushort4(f2bf(av.x), f2bf(av.y), f2bf(av.z), f2bf(av.w));
      }
    } else {
#pragma unroll
      for (int i = 0; i < 2; ++i) {
        const int fi  = (i * 256 + tid) * 8;  // flat bf16 index in 128x32 tile
        const int row = fi >> 5;
        const int col = fi & 31;
        const s16x8 av = *reinterpret_cast<const s16x8*>(A + (size_t)(m0 + row) * K + kt + col);
        *reinterpret_cast<s16x8*>(&As[row * 40 + col]) = av;
      }
    }
    // ---- stage B tile (always fp32 weights) ----
#pragma unroll
    for (int i = 0; i < 4; ++i) {
      const int fi  = (i * 256 + tid) * 4;
      const int row = fi >> 5;
      const int col = fi & 31;
      const float4 bv = *reinterpret_cast<const float4*>(B + (size_t)(n0 + row) * K + kt + col);
      *reinterpret_cast<ushort4*>(&Bs[row * 40 + col]) =
          make_ushort4(f2bf(bv.x), f2bf(bv.y), f2bf(bv.z), f2bf(bv.w));
    }
    __syncthreads();

    // ---- fragments + MFMA ----
    s16x8 afr[4], bfr[4];
#pragma unroll
    for (int mf = 0; mf < 4; ++mf)
      afr[mf] = *reinterpret_cast<const s16x8*>(&As[(wr * 64 + mf * 16 + frow) * 40 + krow]);
#pragma unroll
    for (int nf = 0; nf < 4; ++nf)
      bfr[nf] = *reinterpret_cast<const s16x8*>(&Bs[(wc * 64 + nf * 16 + frow) * 40 + krow]);
#pragma unroll
    for (int mf = 0; mf < 4; ++mf)
#pragma unroll
      for (int nf = 0; nf < 4; ++nf)
        acc[mf][nf] = __builtin_amdgcn_mfma_f32_16x16x32_bf16(afr[mf], bfr[nf], acc[mf][nf], 0, 0, 0);
    __syncthreads();
  }

  // ---- epilogue: C/D layout col = lane&15, row = (lane>>4)*4 + r ----
#pragma unroll
  for (int nf = 0; nf < 4; ++nf) {
    const int col = n0 + wc * 64 + nf * 16 + frow;
    const float bv = bias[col];
#pragma unroll
    for (int mf = 0; mf < 4; ++mf) {
      const int rbase = m0 + wr * 64 + mf * 16 + kq * 4;
#pragma unroll
      for (int r = 0; r < 4; ++r) {
        const float v = acc[mf][nf][r] + bv;
        if constexpr (std::is_same<OT, float>::value)
          C[(size_t)(rbase + r) * N + col] = v;
        else
          C[(size_t)(rbase + r) * N + col] = f2bf(v);
      }
    }
  }
}

// ---------------------------------------------------------------------------
// Scan pass 1: per (b, chunk q, channel j) local scan over 64 steps starting
// from c=0: P = prod f, cl = local response. Summary layout [q][b][j].
// Gates stored bf16.
// ---------------------------------------------------------------------------
__global__ void scan_pass1(const unsigned short* __restrict__ gates,
                           float* __restrict__ P, float* __restrict__ cl) {
  const int t = blockIdx.x * 256 + threadIdx.x;  // 0..262143
  const int j = t & 1023;
  const int q = (t >> 10) & 63;
  const int b = t >> 16;
  const size_t base = ((size_t)(b * 4096 + q * 64)) * 1024 + j;
  const unsigned short* fx = gates;
  const unsigned short* ix = gates + GATE_ELEMS;
  const unsigned short* zx = gates + 2 * GATE_ELEMS;
  float Pp = 1.f, c = 0.f;
  for (int s = 0; s < 64; ++s) {
    const size_t o = base + (size_t)s * 1024;
    const float f = sigmoidf_(bf2f(fx[o]) + 1.f);
    const float u = sigmoidf_(bf2f(ix[o])) * tanhf_(bf2f(zx[o]));
    Pp *= f;
    c = f * c + u;
  }
  const int sidx = q * 4096 + b * 1024 + j;
  P[sidx]  = Pp;
  cl[sidx] = c;
}

// ---------------------------------------------------------------------------
// Scan pass 2: per channel, sequential scan over the 64 chunk summaries.
// Writes the incoming carry for each chunk and last_c to the output.
// ---------------------------------------------------------------------------
__global__ void scan_pass2(const float* __restrict__ P, const float* __restrict__ cl,
                           const float* __restrict__ c0, float* __restrict__ cin,
                           float* __restrict__ lastc) {
  const int idx = blockIdx.x * 256 + threadIdx.x;  // 0..4095 = b*1024 + j
  float carry = c0[idx];
#pragma unroll
  for (int q = 0; q < 64; ++q) {
    const int s = q * 4096 + idx;
    cin[s] = carry;
    carry = fmaf(P[s], carry, cl[s]);
  }
  lastc[idx] = carry;
}

// ---------------------------------------------------------------------------
// Scan pass 3: replay local scan with the correct incoming carry, compute h
// (stored bf16).
// ---------------------------------------------------------------------------
__global__ void scan_pass3(const unsigned short* __restrict__ gates,
                           const float* __restrict__ cin,
                           unsigned short* __restrict__ h,
                           float* __restrict__ lasth) {
  const int t = blockIdx.x * 256 + threadIdx.x;
  const int j = t & 1023;
  const int q = (t >> 10) & 63;
  const int b = t >> 16;
  const size_t base = ((size_t)(b * 4096 + q * 64)) * 1024 + j;
  const unsigned short* fx = gates;
  const unsigned short* ix = gates + GATE_ELEMS;
  const unsigned short* zx = gates + 2 * GATE_ELEMS;
  const unsigned short* ox = gates + 3 * GATE_ELEMS;
  float c = cin[q * 4096 + b * 1024 + j];
  float hv = 0.f;
  for (int s = 0; s < 64; ++s) {
    const size_t o = base + (size_t)s * 1024;
    const float f = sigmoidf_(bf2f(fx[o]) + 1.f);
    const float u = sigmoidf_(bf2f(ix[o])) * tanhf_(bf2f(zx[o]));
    c = f * c + u;
    hv = sigmoidf_(bf2f(ox[o])) * tanhf_(c);
    h[o] = f2bf(hv);
  }
  if (q == 63) lasth[b * 1024 + j] = hv;
}

// ---------------------------------------------------------------------------
extern "C" void kernel_launch(void* const* d_in, const int* in_sizes, int n_in,
                              void* d_out, int out_size, void* d_ws, size_t ws_size,
                              hipStream_t stream) {
  const float* xin[4]  = {(const float*)d_in[0], (const float*)d_in[1],
                          (const float*)d_in[2], (const float*)d_in[3]};
  const float* c0      = (const float*)d_in[4];
  // d_in[5] = h0 is unused by the reference
  const float* W[4]    = {(const float*)d_in[6], (const float*)d_in[8],
                          (const float*)d_in[10], (const float*)d_in[12]};
  const float* bias[4] = {(const float*)d_in[7], (const float*)d_in[9],
                          (const float*)d_in[11], (const float*)d_in[13]};
  const float* Wp = (const float*)d_in[14];
  const float* bp = (const float*)d_in[15];
  float* out = (float*)d_out;

  // Workspace layout:
  //   gates[4] : 4 * 16777216 bf16 (fx, ix, zx, ox pre-activations)  128 MB
  //   h        : 16777216 bf16                                        32 MB
  //   P/cl/cin : 3 * 262144 fp32                                       3 MB
  unsigned short* gates = (unsigned short*)d_ws;
  unsigned short* h     = gates + 4 * GATE_ELEMS;
  float* Pbuf   = (float*)(h + GATE_ELEMS);
  float* clbuf  = Pbuf + 262144;
  float* cinbuf = clbuf + 262144;

  const dim3 gg(8, 128, 1);   // N/128 = 8, M/128 = 128
  for (int g = 0; g < 4; ++g)
    gemm_bt_kernel<float, unsigned short><<<gg, 256, 0, stream>>>(
        xin[g], W[g], bias[g], gates + (size_t)g * GATE_ELEMS, 16384, 1024, 1024);

  scan_pass1<<<1024, 256, 0, stream>>>(gates, Pbuf, clbuf);
  scan_pass2<<<16, 256, 0, stream>>>(Pbuf, clbuf, c0, cinbuf, out + GATE_ELEMS);
  scan_pass3<<<1024, 256, 0, stream>>>(gates, cinbuf, h, out + GATE_ELEMS + 4096);

  gemm_bt_kernel<unsigned short, float><<<gg, 256, 0, stream>>>(
      h, Wp, bp, out, 16384, 1024, 1024);
}

// Round 4
// 671.111 us; speedup vs baseline: 1.1875x; 1.1875x over previous
//
#include <hip/hip_runtime.h>
#include <hip/hip_bf16.h>
#include <type_traits>

// B=4, S=4096, H=1024, NH=8, HD=128, L=64 ; d = NH*HD = 1024
// M = B*S = 16384, K = N = 1024 for all five GEMMs.
#define GATE_ELEMS 16777216ull   // 16384 * 1024
#define W_ELEMS    1048576ull    // 1024 * 1024

typedef float f32x4 __attribute__((ext_vector_type(4)));
typedef short s16x8 __attribute__((ext_vector_type(8)));
typedef unsigned short u16;

__device__ __forceinline__ u16 f2bf(float f) {
  union { float f; unsigned u; } v; v.f = f;
  unsigned r = v.u + 0x7fffu + ((v.u >> 16) & 1u);   // RNE round to bf16
  return (u16)(r >> 16);
}
__device__ __forceinline__ float bf2f(u16 u) {
  union { unsigned u; float f; } v; v.u = ((unsigned)u) << 16;
  return v.f;
}
__device__ __forceinline__ float sigmoidf_(float x) {
  return 1.0f / (1.0f + __expf(-x));
}
__device__ __forceinline__ float tanhf_(float x) {
  x = fminf(fmaxf(x, -15.f), 15.f);
  const float e = __expf(2.f * x);
  return (e - 1.f) / (e + 1.f);
}

__device__ __forceinline__ void load_lds16(const u16* g, u16* l) {
  __builtin_amdgcn_global_load_lds(
      (const __attribute__((address_space(1))) unsigned int*)g,
      (__attribute__((address_space(3))) unsigned int*)l, 16, 0, 0);
}

// ---------------------------------------------------------------------------
// fp32 -> bf16 converts (8 elems/thread, 16B stores)
// ---------------------------------------------------------------------------
__global__ void cvt_x_kernel(const float* __restrict__ x0, const float* __restrict__ x1,
                             const float* __restrict__ x2, const float* __restrict__ x3,
                             u16* __restrict__ dst) {
  const float* src = (blockIdx.y == 0) ? x0 : (blockIdx.y == 1) ? x1
                   : (blockIdx.y == 2) ? x2 : x3;
  u16* d = dst + (size_t)blockIdx.y * GATE_ELEMS;
  const size_t i = ((size_t)blockIdx.x * 256 + threadIdx.x) * 8;
  const float4 a = *reinterpret_cast<const float4*>(src + i);
  const float4 b = *reinterpret_cast<const float4*>(src + i + 4);
  ushort4 lo = make_ushort4(f2bf(a.x), f2bf(a.y), f2bf(a.z), f2bf(a.w));
  ushort4 hi = make_ushort4(f2bf(b.x), f2bf(b.y), f2bf(b.z), f2bf(b.w));
  *reinterpret_cast<ushort4*>(d + i)     = lo;
  *reinterpret_cast<ushort4*>(d + i + 4) = hi;
}

__global__ void cvt_w_kernel(const float* __restrict__ w0, const float* __restrict__ w1,
                             const float* __restrict__ w2, const float* __restrict__ w3,
                             const float* __restrict__ w4, u16* __restrict__ dst) {
  const float* src = (blockIdx.y == 0) ? w0 : (blockIdx.y == 1) ? w1
                   : (blockIdx.y == 2) ? w2 : (blockIdx.y == 3) ? w3 : w4;
  u16* d = dst + (size_t)blockIdx.y * W_ELEMS;
  const size_t i = ((size_t)blockIdx.x * 256 + threadIdx.x) * 8;
  const float4 a = *reinterpret_cast<const float4*>(src + i);
  const float4 b = *reinterpret_cast<const float4*>(src + i + 4);
  ushort4 lo = make_ushort4(f2bf(a.x), f2bf(a.y), f2bf(a.z), f2bf(a.w));
  ushort4 hi = make_ushort4(f2bf(b.x), f2bf(b.y), f2bf(b.z), f2bf(b.w));
  *reinterpret_cast<ushort4*>(d + i)     = lo;
  *reinterpret_cast<ushort4*>(d + i + 4) = hi;
}

// ---------------------------------------------------------------------------
// bf16 GEMM (m97 structure): C[m,n] = sum_k A[m,k]*B[n,k] + bias[n]
// A: M x K bf16 row-major, B: N x K bf16 row-major.
// 128x128 tile, BK=32, linear [128][32] LDS, global_load_lds width=16,
// 4 waves (2x2), 4x4 x (16x16x32) MFMA per wave, XCD-swizzled 1-D grid.
// ---------------------------------------------------------------------------
template <typename OT>
__global__ __launch_bounds__(256, 3)
void gemm_bt_bf16(const u16* __restrict__ A, const u16* __restrict__ B,
                  const float* __restrict__ bias, OT* __restrict__ C,
                  int M, int N, int K) {
  __shared__ __align__(16) u16 As[128 * 32];
  __shared__ __align__(16) u16 Bs[128 * 32];
  const int tid  = threadIdx.x;
  const int lane = tid & 63;
  const int wave = tid >> 6;
  const int wr = wave >> 1;
  const int wc = wave & 1;

  // bijective XCD swizzle (gridDim.x % 8 == 0)
  const int cpx = gridDim.x >> 3;
  int bid = blockIdx.x;
  bid = (bid & 7) * cpx + (bid >> 3);
  const int nbx = N >> 7;
  const int m0 = (bid / nbx) * 128;
  const int n0 = (bid % nbx) * 128;

  f32x4 acc[4][4];
#pragma unroll
  for (int i = 0; i < 4; ++i)
#pragma unroll
    for (int j = 0; j < 4; ++j)
      acc[i][j] = (f32x4){0.f, 0.f, 0.f, 0.f};

  const int frow = lane & 15;        // fragment row (A) / col (B)
  const int kq   = lane >> 4;        // k-quadrant
  const int krow = kq * 8;

  const int lrow = lane >> 2;        // staging: row within 16-row slab
  const int lcol = (lane & 3) * 8;   // staging: bf16 col 0/8/16/24

  for (int kt = 0; kt < K; kt += 32) {
#pragma unroll
    for (int i = 0; i < 2; ++i) {
      const int rb = (i * 4 + wave) * 16;            // 16-row slab base
      load_lds16(A + (size_t)(m0 + rb + lrow) * K + kt + lcol, &As[rb * 32]);
      load_lds16(B + (size_t)(n0 + rb + lrow) * K + kt + lcol, &Bs[rb * 32]);
    }
    __syncthreads();

    s16x8 afr[4], bfr[4];
#pragma unroll
    for (int mf = 0; mf < 4; ++mf)
      afr[mf] = *reinterpret_cast<const s16x8*>(&As[(wr * 64 + mf * 16 + frow) * 32 + krow]);
#pragma unroll
    for (int nf = 0; nf < 4; ++nf)
      bfr[nf] = *reinterpret_cast<const s16x8*>(&Bs[(wc * 64 + nf * 16 + frow) * 32 + krow]);
#pragma unroll
    for (int mf = 0; mf < 4; ++mf)
#pragma unroll
      for (int nf = 0; nf < 4; ++nf)
        acc[mf][nf] = __builtin_amdgcn_mfma_f32_16x16x32_bf16(afr[mf], bfr[nf], acc[mf][nf], 0, 0, 0);
    __syncthreads();
  }

  // epilogue: C/D layout col = lane&15, row = (lane>>4)*4 + r
#pragma unroll
  for (int nf = 0; nf < 4; ++nf) {
    const int col = n0 + wc * 64 + nf * 16 + frow;
    const float bv = bias[col];
#pragma unroll
    for (int mf = 0; mf < 4; ++mf) {
      const int rbase = m0 + wr * 64 + mf * 16 + kq * 4;
#pragma unroll
      for (int r = 0; r < 4; ++r) {
        const float v = acc[mf][nf][r] + bv;
        if constexpr (std::is_same<OT, float>::value)
          C[(size_t)(rbase + r) * N + col] = v;
        else
          C[(size_t)(rbase + r) * N + col] = f2bf(v);
      }
    }
  }
}

// ---------------------------------------------------------------------------
// Scan pass 1: 4 channels/thread. P = prod f, cl = local response (c0=0).
// Summary layout [q][b][j].
// ---------------------------------------------------------------------------
__global__ void scan_pass1(const u16* __restrict__ fx, const u16* __restrict__ ix,
                           const u16* __restrict__ zx,
                           float* __restrict__ P, float* __restrict__ cl) {
  const int t  = blockIdx.x * 256 + threadIdx.x;   // 0..65535
  const int jg = (t & 255) * 4;
  const int q  = (t >> 8) & 63;
  const int b  = t >> 14;
  const size_t base = ((size_t)(b * 4096 + q * 64)) * 1024 + jg;
  float Pp[4] = {1.f, 1.f, 1.f, 1.f};
  float c[4]  = {0.f, 0.f, 0.f, 0.f};
  for (int s = 0; s < 64; ++s) {
    const size_t o = base + (size_t)s * 1024;
    const ushort4 fv = *reinterpret_cast<const ushort4*>(fx + o);
    const ushort4 iv = *reinterpret_cast<const ushort4*>(ix + o);
    const ushort4 zv = *reinterpret_cast<const ushort4*>(zx + o);
    const u16* fp = (const u16*)&fv;
    const u16* ip = (const u16*)&iv;
    const u16* zp = (const u16*)&zv;
#pragma unroll
    for (int k = 0; k < 4; ++k) {
      const float f = sigmoidf_(bf2f(fp[k]) + 1.f);
      const float u = sigmoidf_(bf2f(ip[k])) * tanhf_(bf2f(zp[k]));
      Pp[k] *= f;
      c[k] = f * c[k] + u;
    }
  }
  const int sidx = q * 4096 + b * 1024 + jg;
  *reinterpret_cast<float4*>(P + sidx)  = make_float4(Pp[0], Pp[1], Pp[2], Pp[3]);
  *reinterpret_cast<float4*>(cl + sidx) = make_float4(c[0], c[1], c[2], c[3]);
}

// ---------------------------------------------------------------------------
// Scan pass 2: per-channel scan over 64 chunk summaries; emits carries + last_c.
// ---------------------------------------------------------------------------
__global__ void scan_pass2(const float* __restrict__ P, const float* __restrict__ cl,
                           const float* __restrict__ c0, float* __restrict__ cin,
                           float* __restrict__ lastc) {
  const int idx = blockIdx.x * 256 + threadIdx.x;  // 0..4095
  float carry = c0[idx];
#pragma unroll
  for (int q = 0; q < 64; ++q) {
    const int s = q * 4096 + idx;
    cin[s] = carry;
    carry = fmaf(P[s], carry, cl[s]);
  }
  lastc[idx] = carry;
}

// ---------------------------------------------------------------------------
// Scan pass 3: replay with correct carry, compute h (bf16) + last_h.
// ---------------------------------------------------------------------------
__global__ void scan_pass3(const u16* __restrict__ fx, const u16* __restrict__ ix,
                           const u16* __restrict__ zx, const u16* __restrict__ ox,
                           const float* __restrict__ cin,
                           u16* __restrict__ h, float* __restrict__ lasth) {
  const int t  = blockIdx.x * 256 + threadIdx.x;
  const int jg = (t & 255) * 4;
  const int q  = (t >> 8) & 63;
  const int b  = t >> 14;
  const size_t base = ((size_t)(b * 4096 + q * 64)) * 1024 + jg;
  const float4 ci = *reinterpret_cast<const float4*>(cin + q * 4096 + b * 1024 + jg);
  float c[4]  = {ci.x, ci.y, ci.z, ci.w};
  float hv[4] = {0.f, 0.f, 0.f, 0.f};
  for (int s = 0; s < 64; ++s) {
    const size_t o = base + (size_t)s * 1024;
    const ushort4 fv = *reinterpret_cast<const ushort4*>(fx + o);
    const ushort4 iv = *reinterpret_cast<const ushort4*>(ix + o);
    const ushort4 zv = *reinterpret_cast<const ushort4*>(zx + o);
    const ushort4 ov = *reinterpret_cast<const ushort4*>(ox + o);
    const u16* fp = (const u16*)&fv;
    const u16* ip = (const u16*)&iv;
    const u16* zp = (const u16*)&zv;
    const u16* op = (const u16*)&ov;
    ushort4 hw;
    u16* hp = (u16*)&hw;
#pragma unroll
    for (int k = 0; k < 4; ++k) {
      const float f = sigmoidf_(bf2f(fp[k]) + 1.f);
      const float u = sigmoidf_(bf2f(ip[k])) * tanhf_(bf2f(zp[k]));
      c[k] = f * c[k] + u;
      hv[k] = sigmoidf_(bf2f(op[k])) * tanhf_(c[k]);
      hp[k] = f2bf(hv[k]);
    }
    *reinterpret_cast<ushort4*>(h + o) = hw;
  }
  if (q == 63)
    *reinterpret_cast<float4*>(lasth + b * 1024 + jg) =
        make_float4(hv[0], hv[1], hv[2], hv[3]);
}

// ---------------------------------------------------------------------------
extern "C" void kernel_launch(void* const* d_in, const int* in_sizes, int n_in,
                              void* d_out, int out_size, void* d_ws, size_t ws_size,
                              hipStream_t stream) {
  const float* xin[4]  = {(const float*)d_in[0], (const float*)d_in[1],
                          (const float*)d_in[2], (const float*)d_in[3]};
  const float* c0      = (const float*)d_in[4];
  const float* W[5]    = {(const float*)d_in[6], (const float*)d_in[8],
                          (const float*)d_in[10], (const float*)d_in[12],
                          (const float*)d_in[14]};
  const float* bias[5] = {(const float*)d_in[7], (const float*)d_in[9],
                          (const float*)d_in[11], (const float*)d_in[13],
                          (const float*)d_in[15]};
  float* out = (float*)d_out;

  // Workspace (~149 MB):
  //   xbf[4]  : bf16 copies of the four X inputs (each reused as a gate buffer
  //             once consumed, h goes into xbf[3])
  //   wbf[5]  : bf16 weights
  //   P/cl/cin: chunk summaries
  // gate0 lives in d_out scratch (bf16, 32 MB < 64 MB y region), consumed by
  // pass1/pass3 before the final GEMM overwrites it.
  u16* xbf = (u16*)d_ws;
  u16* wbf = xbf + 4 * GATE_ELEMS;
  float* Pbuf   = (float*)(wbf + 5 * W_ELEMS);
  float* clbuf  = Pbuf + 262144;
  float* cinbuf = clbuf + 262144;

  u16* gp[4];
  gp[0] = (u16*)d_out;
  gp[1] = xbf;                    // dead after GEMM 0? no: dead after GEMM 0 consumed xbf[0]
  gp[2] = xbf + GATE_ELEMS;
  gp[3] = xbf + 2 * GATE_ELEMS;
  u16* h = xbf + 3 * GATE_ELEMS;  // dead after GEMM 3

  cvt_x_kernel<<<dim3(8192, 4), 256, 0, stream>>>(xin[0], xin[1], xin[2], xin[3], xbf);
  cvt_w_kernel<<<dim3(512, 5), 256, 0, stream>>>(W[0], W[1], W[2], W[3], W[4], wbf);

  // GEMM g reads xbf[g]; its output goes to a buffer whose previous content
  // is dead by launch order: g0->d_out, g1->xbf[0], g2->xbf[1], g3->xbf[2].
  const dim3 gg(1024, 1, 1);
  for (int g = 0; g < 4; ++g)
    gemm_bt_bf16<u16><<<gg, 256, 0, stream>>>(
        xbf + (size_t)g * GATE_ELEMS, wbf + (size_t)g * W_ELEMS, bias[g],
        gp[g], 16384, 1024, 1024);

  scan_pass1<<<256, 256, 0, stream>>>(gp[0], gp[1], gp[2], Pbuf, clbuf);
  scan_pass2<<<16, 256, 0, stream>>>(Pbuf, clbuf, c0, cinbuf, out + GATE_ELEMS);
  scan_pass3<<<256, 256, 0, stream>>>(gp[0], gp[1], gp[2], gp[3], cinbuf, h,
                                      out + GATE_ELEMS + 4096);

  gemm_bt_bf16<float><<<gg, 256, 0, stream>>>(h, wbf + 4 * W_ELEMS, bias[4],
                                              out, 16384, 1024, 1024);
}

// Round 5
// 648.901 us; speedup vs baseline: 1.2281x; 1.0342x over previous
//
#include <hip/hip_runtime.h>
#include <hip/hip_bf16.h>
#include <type_traits>

// B=4, S=4096, H=1024, NH=8, HD=128, L=64 ; d = NH*HD = 1024
// M = B*S = 16384, K = N = 1024 for all five GEMMs.
#define GATE_ELEMS 16777216ull   // 16384 * 1024
#define W_ELEMS    1048576ull    // 1024 * 1024

typedef float f32x4 __attribute__((ext_vector_type(4)));
typedef short s16x8 __attribute__((ext_vector_type(8)));
typedef unsigned short u16;

__device__ __forceinline__ u16 f2bf(float f) {
  union { float f; unsigned u; } v; v.f = f;
  unsigned r = v.u + 0x7fffu + ((v.u >> 16) & 1u);   // RNE round to bf16
  return (u16)(r >> 16);
}
__device__ __forceinline__ float bf2f(u16 u) {
  union { unsigned u; float f; } v; v.u = ((unsigned)u) << 16;
  return v.f;
}
__device__ __forceinline__ float sigmoidf_(float x) {
  return 1.0f / (1.0f + __expf(-x));
}
__device__ __forceinline__ float tanhf_(float x) {
  x = fminf(fmaxf(x, -15.f), 15.f);
  const float e = __expf(2.f * x);
  return (e - 1.f) / (e + 1.f);
}

__device__ __forceinline__ void load_lds16(const u16* g, u16* l) {
  __builtin_amdgcn_global_load_lds(
      (const __attribute__((address_space(1))) unsigned int*)g,
      (__attribute__((address_space(3))) unsigned int*)l, 16, 0, 0);
}

// ---------------------------------------------------------------------------
// fp32 -> bf16 converts
// ---------------------------------------------------------------------------
__global__ void cvt_x_kernel(const float* __restrict__ x0, const float* __restrict__ x1,
                             const float* __restrict__ x2, const float* __restrict__ x3,
                             u16* __restrict__ dst) {
  const float* src = (blockIdx.y == 0) ? x0 : (blockIdx.y == 1) ? x1
                   : (blockIdx.y == 2) ? x2 : x3;
  u16* d = dst + (size_t)blockIdx.y * GATE_ELEMS;
  const size_t i = ((size_t)blockIdx.x * 256 + threadIdx.x) * 16;
#pragma unroll
  for (int half = 0; half < 2; ++half) {
    const float4 a = *reinterpret_cast<const float4*>(src + i + half * 8);
    const float4 b = *reinterpret_cast<const float4*>(src + i + half * 8 + 4);
    s16x8 w;
    w[0] = (short)f2bf(a.x); w[1] = (short)f2bf(a.y);
    w[2] = (short)f2bf(a.z); w[3] = (short)f2bf(a.w);
    w[4] = (short)f2bf(b.x); w[5] = (short)f2bf(b.y);
    w[6] = (short)f2bf(b.z); w[7] = (short)f2bf(b.w);
    *reinterpret_cast<s16x8*>(d + i + half * 8) = w;
  }
}

__global__ void cvt_w_kernel(const float* __restrict__ w0, const float* __restrict__ w1,
                             const float* __restrict__ w2, const float* __restrict__ w3,
                             const float* __restrict__ w4, u16* __restrict__ dst) {
  const float* src = (blockIdx.y == 0) ? w0 : (blockIdx.y == 1) ? w1
                   : (blockIdx.y == 2) ? w2 : (blockIdx.y == 3) ? w3 : w4;
  u16* d = dst + (size_t)blockIdx.y * W_ELEMS;
  const size_t i = ((size_t)blockIdx.x * 256 + threadIdx.x) * 8;
  const float4 a = *reinterpret_cast<const float4*>(src + i);
  const float4 b = *reinterpret_cast<const float4*>(src + i + 4);
  s16x8 w;
  w[0] = (short)f2bf(a.x); w[1] = (short)f2bf(a.y);
  w[2] = (short)f2bf(a.z); w[3] = (short)f2bf(a.w);
  w[4] = (short)f2bf(b.x); w[5] = (short)f2bf(b.y);
  w[6] = (short)f2bf(b.z); w[7] = (short)f2bf(b.w);
  *reinterpret_cast<s16x8*>(d + i) = w;
}

// ---------------------------------------------------------------------------
// 256x256-tile bf16 GEMM, 8 waves (2M x 4N), BK=32, 16-slot LDS ring (128 KiB)
// with 3-K-tile prefetch and counted vmcnt(8) at K-tile boundaries.
// C[m,n] = sum_k A[m,k]*B[n,k] + bias[n];  M=16384, N=1024, K=1024 fixed.
// Half-tiles (8 KB): 0 = A rows [0,128), 1 = A rows [128,256), 2 = B rows
// [0,128), 3 = B rows [128,256). Slot(kt,hp) = (kt&3)*4 + hp.
// ---------------------------------------------------------------------------
__device__ __forceinline__ void stage_half(
    const u16* __restrict__ A, const u16* __restrict__ B,
    int m0, int n0, int kt, int hp, u16* lds, int tid) {
  const u16* mat = (hp < 2) ? A : B;
  const int gr0 = ((hp < 2) ? m0 : n0) + (hp & 1) * 128;
  const int o   = tid * 16;            // byte offset within the 8 KB half
  const int row = o >> 6;              // 64 B per row (BK=32 bf16)
  const int col = (o & 63) >> 1;       // element col 0..31
  const int slot = ((kt & 3) * 4 + hp) * 4096;  // u16 units (8 KB slots)
  load_lds16(mat + (size_t)(gr0 + row) * 1024 + kt * 32 + col,
             lds + slot + (tid >> 6) * 512);     // wave-uniform base; HW adds lane*16B
}

template <typename OT>
__global__ __launch_bounds__(512, 2)
void gemm_256(const u16* __restrict__ A, const u16* __restrict__ B,
              const float* __restrict__ bias, OT* __restrict__ C) {
  extern __shared__ u16 lds[];         // 16 slots * 4096 u16 = 131072 B
  const int tid  = threadIdx.x;
  const int lane = tid & 63;
  const int wave = tid >> 6;
  const int wm = wave >> 2;            // 0..1 -> 128-row slab
  const int wn = wave & 3;             // 0..3 -> 64-col slab
  const int frow = lane & 15;
  const int kq   = lane >> 4;          // 0..3

  // bijective XCD swizzle; grid = 256 (64 m-tiles x 4 n-tiles), m-major
  int bid = blockIdx.x;
  bid = (bid & 7) * 32 + (bid >> 3);
  const int m0 = (bid >> 2) * 256;
  const int n0 = (bid & 3) * 256;

  f32x4 acc[8][4];
#pragma unroll
  for (int i = 0; i < 8; ++i)
#pragma unroll
    for (int j = 0; j < 4; ++j)
      acc[i][j] = (f32x4){0.f, 0.f, 0.f, 0.f};

  // prologue: stage K-tiles 0,1,2 (12 half-tiles); leave kt1,kt2 in flight
#pragma unroll
  for (int k = 0; k < 3; ++k)
#pragma unroll
    for (int hp = 0; hp < 4; ++hp)
      stage_half(A, B, m0, n0, k, hp, lds, tid);
  asm volatile("s_waitcnt vmcnt(8)" ::: "memory");
  __builtin_amdgcn_s_barrier();

  const int rb = (wn & 1) * 64;        // B row offset within its half

#pragma unroll 4
  for (int kt = 0; kt < 32; ++kt) {
    const int slotbase = (kt & 3) * 4;
    const u16* Ar = lds + (slotbase + wm) * 4096;
    const u16* Br = lds + (slotbase + 2 + (wn >> 1)) * 4096;

    // ---- phase 0: frags A[mf0-3], B[nf0-3]; stage halves 0,1 of kt+3 ----
    s16x8 a0 = *reinterpret_cast<const s16x8*>(&Ar[(0 * 16 + frow) * 32 + kq * 8]);
    s16x8 a1 = *reinterpret_cast<const s16x8*>(&Ar[(1 * 16 + frow) * 32 + kq * 8]);
    s16x8 a2 = *reinterpret_cast<const s16x8*>(&Ar[(2 * 16 + frow) * 32 + kq * 8]);
    s16x8 a3 = *reinterpret_cast<const s16x8*>(&Ar[(3 * 16 + frow) * 32 + kq * 8]);
    s16x8 b0 = *reinterpret_cast<const s16x8*>(&Br[(rb + 0 * 16 + frow) * 32 + kq * 8]);
    s16x8 b1 = *reinterpret_cast<const s16x8*>(&Br[(rb + 1 * 16 + frow) * 32 + kq * 8]);
    s16x8 b2 = *reinterpret_cast<const s16x8*>(&Br[(rb + 2 * 16 + frow) * 32 + kq * 8]);
    s16x8 b3 = *reinterpret_cast<const s16x8*>(&Br[(rb + 3 * 16 + frow) * 32 + kq * 8]);
    if (kt <= 28) {
      stage_half(A, B, m0, n0, kt + 3, 0, lds, tid);
      stage_half(A, B, m0, n0, kt + 3, 1, lds, tid);
    }
    __builtin_amdgcn_s_barrier();
    asm volatile("s_waitcnt lgkmcnt(0)" ::: "memory");
    __builtin_amdgcn_sched_barrier(0);
    __builtin_amdgcn_s_setprio(1);
    acc[0][0] = __builtin_amdgcn_mfma_f32_16x16x32_bf16(a0, b0, acc[0][0], 0, 0, 0);
    acc[0][1] = __builtin_amdgcn_mfma_f32_16x16x32_bf16(a0, b1, acc[0][1], 0, 0, 0);
    acc[0][2] = __builtin_amdgcn_mfma_f32_16x16x32_bf16(a0, b2, acc[0][2], 0, 0, 0);
    acc[0][3] = __builtin_amdgcn_mfma_f32_16x16x32_bf16(a0, b3, acc[0][3], 0, 0, 0);
    acc[1][0] = __builtin_amdgcn_mfma_f32_16x16x32_bf16(a1, b0, acc[1][0], 0, 0, 0);
    acc[1][1] = __builtin_amdgcn_mfma_f32_16x16x32_bf16(a1, b1, acc[1][1], 0, 0, 0);
    acc[1][2] = __builtin_amdgcn_mfma_f32_16x16x32_bf16(a1, b2, acc[1][2], 0, 0, 0);
    acc[1][3] = __builtin_amdgcn_mfma_f32_16x16x32_bf16(a1, b3, acc[1][3], 0, 0, 0);
    acc[2][0] = __builtin_amdgcn_mfma_f32_16x16x32_bf16(a2, b0, acc[2][0], 0, 0, 0);
    acc[2][1] = __builtin_amdgcn_mfma_f32_16x16x32_bf16(a2, b1, acc[2][1], 0, 0, 0);
    acc[2][2] = __builtin_amdgcn_mfma_f32_16x16x32_bf16(a2, b2, acc[2][2], 0, 0, 0);
    acc[2][3] = __builtin_amdgcn_mfma_f32_16x16x32_bf16(a2, b3, acc[2][3], 0, 0, 0);
    acc[3][0] = __builtin_amdgcn_mfma_f32_16x16x32_bf16(a3, b0, acc[3][0], 0, 0, 0);
    acc[3][1] = __builtin_amdgcn_mfma_f32_16x16x32_bf16(a3, b1, acc[3][1], 0, 0, 0);
    acc[3][2] = __builtin_amdgcn_mfma_f32_16x16x32_bf16(a3, b2, acc[3][2], 0, 0, 0);
    acc[3][3] = __builtin_amdgcn_mfma_f32_16x16x32_bf16(a3, b3, acc[3][3], 0, 0, 0);
    __builtin_amdgcn_s_setprio(0);
    __builtin_amdgcn_sched_barrier(0);
    __builtin_amdgcn_s_barrier();

    // ---- phase 1: frags A[mf4-7] (B held); stage halves 2,3 of kt+3 ----
    a0 = *reinterpret_cast<const s16x8*>(&Ar[(4 * 16 + frow) * 32 + kq * 8]);
    a1 = *reinterpret_cast<const s16x8*>(&Ar[(5 * 16 + frow) * 32 + kq * 8]);
    a2 = *reinterpret_cast<const s16x8*>(&Ar[(6 * 16 + frow) * 32 + kq * 8]);
    a3 = *reinterpret_cast<const s16x8*>(&Ar[(7 * 16 + frow) * 32 + kq * 8]);
    if (kt <= 28) {
      stage_half(A, B, m0, n0, kt + 3, 2, lds, tid);
      stage_half(A, B, m0, n0, kt + 3, 3, lds, tid);
    }
    __builtin_amdgcn_s_barrier();
    asm volatile("s_waitcnt lgkmcnt(0)" ::: "memory");
    __builtin_amdgcn_sched_barrier(0);
    __builtin_amdgcn_s_setprio(1);
    acc[4][0] = __builtin_amdgcn_mfma_f32_16x16x32_bf16(a0, b0, acc[4][0], 0, 0, 0);
    acc[4][1] = __builtin_amdgcn_mfma_f32_16x16x32_bf16(a0, b1, acc[4][1], 0, 0, 0);
    acc[4][2] = __builtin_amdgcn_mfma_f32_16x16x32_bf16(a0, b2, acc[4][2], 0, 0, 0);
    acc[4][3] = __builtin_amdgcn_mfma_f32_16x16x32_bf16(a0, b3, acc[4][3], 0, 0, 0);
    acc[5][0] = __builtin_amdgcn_mfma_f32_16x16x32_bf16(a1, b0, acc[5][0], 0, 0, 0);
    acc[5][1] = __builtin_amdgcn_mfma_f32_16x16x32_bf16(a1, b1, acc[5][1], 0, 0, 0);
    acc[5][2] = __builtin_amdgcn_mfma_f32_16x16x32_bf16(a1, b2, acc[5][2], 0, 0, 0);
    acc[5][3] = __builtin_amdgcn_mfma_f32_16x16x32_bf16(a1, b3, acc[5][3], 0, 0, 0);
    acc[6][0] = __builtin_amdgcn_mfma_f32_16x16x32_bf16(a2, b0, acc[6][0], 0, 0, 0);
    acc[6][1] = __builtin_amdgcn_mfma_f32_16x16x32_bf16(a2, b1, acc[6][1], 0, 0, 0);
    acc[6][2] = __builtin_amdgcn_mfma_f32_16x16x32_bf16(a2, b2, acc[6][2], 0, 0, 0);
    acc[6][3] = __builtin_amdgcn_mfma_f32_16x16x32_bf16(a2, b3, acc[6][3], 0, 0, 0);
    acc[7][0] = __builtin_amdgcn_mfma_f32_16x16x32_bf16(a3, b0, acc[7][0], 0, 0, 0);
    acc[7][1] = __builtin_amdgcn_mfma_f32_16x16x32_bf16(a3, b1, acc[7][1], 0, 0, 0);
    acc[7][2] = __builtin_amdgcn_mfma_f32_16x16x32_bf16(a3, b2, acc[7][2], 0, 0, 0);
    acc[7][3] = __builtin_amdgcn_mfma_f32_16x16x32_bf16(a3, b3, acc[7][3], 0, 0, 0);
    __builtin_amdgcn_s_setprio(0);
    __builtin_amdgcn_sched_barrier(0);
    // counted vmcnt at K-tile boundary: 2 K-tiles (8 loads) stay in flight
    if (kt <= 28)      asm volatile("s_waitcnt vmcnt(8)" ::: "memory");
    else if (kt == 29) asm volatile("s_waitcnt vmcnt(4)" ::: "memory");
    else if (kt == 30) asm volatile("s_waitcnt vmcnt(0)" ::: "memory");
    __builtin_amdgcn_s_barrier();
  }

  // epilogue: C/D layout col = lane&15, row = (lane>>4)*4 + r
#pragma unroll
  for (int nf = 0; nf < 4; ++nf) {
    const int col = n0 + wn * 64 + nf * 16 + frow;
    const float bv = bias[col];
#pragma unroll
    for (int mf = 0; mf < 8; ++mf) {
      const int rbase = m0 + wm * 128 + mf * 16 + kq * 4;
#pragma unroll
      for (int r = 0; r < 4; ++r) {
        const float v = acc[mf][nf][r] + bv;
        if constexpr (std::is_same<OT, float>::value)
          C[(size_t)(rbase + r) * 1024 + col] = v;
        else
          C[(size_t)(rbase + r) * 1024 + col] = f2bf(v);
      }
    }
  }
}

// ---------------------------------------------------------------------------
// Scan pass 1: 4 channels/thread. P = prod f, cl = local response (c0=0).
// ---------------------------------------------------------------------------
__global__ void scan_pass1(const u16* __restrict__ fx, const u16* __restrict__ ix,
                           const u16* __restrict__ zx,
                           float* __restrict__ P, float* __restrict__ cl) {
  const int t  = blockIdx.x * 256 + threadIdx.x;   // 0..65535
  const int jg = (t & 255) * 4;
  const int q  = (t >> 8) & 63;
  const int b  = t >> 14;
  const size_t base = ((size_t)(b * 4096 + q * 64)) * 1024 + jg;
  float Pp[4] = {1.f, 1.f, 1.f, 1.f};
  float c[4]  = {0.f, 0.f, 0.f, 0.f};
  for (int s = 0; s < 64; ++s) {
    const size_t o = base + (size_t)s * 1024;
    const ushort4 fv = *reinterpret_cast<const ushort4*>(fx + o);
    const ushort4 iv = *reinterpret_cast<const ushort4*>(ix + o);
    const ushort4 zv = *reinterpret_cast<const ushort4*>(zx + o);
    const u16* fp = (const u16*)&fv;
    const u16* ip = (const u16*)&iv;
    const u16* zp = (const u16*)&zv;
#pragma unroll
    for (int k = 0; k < 4; ++k) {
      const float f = sigmoidf_(bf2f(fp[k]) + 1.f);
      const float u = sigmoidf_(bf2f(ip[k])) * tanhf_(bf2f(zp[k]));
      Pp[k] *= f;
      c[k] = f * c[k] + u;
    }
  }
  const int sidx = q * 4096 + b * 1024 + jg;
  *reinterpret_cast<float4*>(P + sidx)  = make_float4(Pp[0], Pp[1], Pp[2], Pp[3]);
  *reinterpret_cast<float4*>(cl + sidx) = make_float4(c[0], c[1], c[2], c[3]);
}

// ---------------------------------------------------------------------------
// Scan pass 2: per-channel scan over 64 chunk summaries; carries + last_c.
// ---------------------------------------------------------------------------
__global__ void scan_pass2(const float* __restrict__ P, const float* __restrict__ cl,
                           const float* __restrict__ c0, float* __restrict__ cin,
                           float* __restrict__ lastc) {
  const int idx = blockIdx.x * 256 + threadIdx.x;  // 0..4095
  float carry = c0[idx];
#pragma unroll
  for (int q = 0; q < 64; ++q) {
    const int s = q * 4096 + idx;
    cin[s] = carry;
    carry = fmaf(P[s], carry, cl[s]);
  }
  lastc[idx] = carry;
}

// ---------------------------------------------------------------------------
// Scan pass 3: replay with correct carry, compute h (bf16) + last_h.
// ---------------------------------------------------------------------------
__global__ void scan_pass3(const u16* __restrict__ fx, const u16* __restrict__ ix,
                           const u16* __restrict__ zx, const u16* __restrict__ ox,
                           const float* __restrict__ cin,
                           u16* __restrict__ h, float* __restrict__ lasth) {
  const int t  = blockIdx.x * 256 + threadIdx.x;
  const int jg = (t & 255) * 4;
  const int q  = (t >> 8) & 63;
  const int b  = t >> 14;
  const size_t base = ((size_t)(b * 4096 + q * 64)) * 1024 + jg;
  const float4 ci = *reinterpret_cast<const float4*>(cin + q * 4096 + b * 1024 + jg);
  float c[4]  = {ci.x, ci.y, ci.z, ci.w};
  float hv[4] = {0.f, 0.f, 0.f, 0.f};
  for (int s = 0; s < 64; ++s) {
    const size_t o = base + (size_t)s * 1024;
    const ushort4 fv = *reinterpret_cast<const ushort4*>(fx + o);
    const ushort4 iv = *reinterpret_cast<const ushort4*>(ix + o);
    const ushort4 zv = *reinterpret_cast<const ushort4*>(zx + o);
    const ushort4 ov = *reinterpret_cast<const ushort4*>(ox + o);
    const u16* fp = (const u16*)&fv;
    const u16* ip = (const u16*)&iv;
    const u16* zp = (const u16*)&zv;
    const u16* op = (const u16*)&ov;
    ushort4 hw;
    u16* hp = (u16*)&hw;
#pragma unroll
    for (int k = 0; k < 4; ++k) {
      const float f = sigmoidf_(bf2f(fp[k]) + 1.f);
      const float u = sigmoidf_(bf2f(ip[k])) * tanhf_(bf2f(zp[k]));
      c[k] = f * c[k] + u;
      hv[k] = sigmoidf_(bf2f(op[k])) * tanhf_(c[k]);
      hp[k] = f2bf(hv[k]);
    }
    *reinterpret_cast<ushort4*>(h + o) = hw;
  }
  if (q == 63)
    *reinterpret_cast<float4*>(lasth + b * 1024 + jg) =
        make_float4(hv[0], hv[1], hv[2], hv[3]);
}

// ---------------------------------------------------------------------------
extern "C" void kernel_launch(void* const* d_in, const int* in_sizes, int n_in,
                              void* d_out, int out_size, void* d_ws, size_t ws_size,
                              hipStream_t stream) {
  const float* xin[4]  = {(const float*)d_in[0], (const float*)d_in[1],
                          (const float*)d_in[2], (const float*)d_in[3]};
  const float* c0      = (const float*)d_in[4];
  const float* W[5]    = {(const float*)d_in[6], (const float*)d_in[8],
                          (const float*)d_in[10], (const float*)d_in[12],
                          (const float*)d_in[14]};
  const float* bias[5] = {(const float*)d_in[7], (const float*)d_in[9],
                          (const float*)d_in[11], (const float*)d_in[13],
                          (const float*)d_in[15]};
  float* out = (float*)d_out;

  // allow 128 KiB dynamic LDS (idempotent; errors ignorable)
  (void)hipFuncSetAttribute((const void*)gemm_256<u16>,
                            hipFuncAttributeMaxDynamicSharedMemorySize, 131072);
  (void)hipFuncSetAttribute((const void*)gemm_256<float>,
                            hipFuncAttributeMaxDynamicSharedMemorySize, 131072);

  // Workspace (~149 MB): xbf[4] (reused as gate buffers / h), wbf[5], summaries.
  u16* xbf = (u16*)d_ws;
  u16* wbf = xbf + 4 * GATE_ELEMS;
  float* Pbuf   = (float*)(wbf + 5 * W_ELEMS);
  float* clbuf  = Pbuf + 262144;
  float* cinbuf = clbuf + 262144;

  u16* gp[4];
  gp[0] = (u16*)d_out;            // gate0 in d_out scratch (consumed pre-final-GEMM)
  gp[1] = xbf;                    // xbf[0] dead after GEMM 0
  gp[2] = xbf + GATE_ELEMS;       // xbf[1] dead after GEMM 1
  gp[3] = xbf + 2 * GATE_ELEMS;   // xbf[2] dead after GEMM 2
  u16* h = xbf + 3 * GATE_ELEMS;  // xbf[3] dead after GEMM 3

  cvt_x_kernel<<<dim3(4096, 4), 256, 0, stream>>>(xin[0], xin[1], xin[2], xin[3], xbf);
  cvt_w_kernel<<<dim3(512, 5), 256, 0, stream>>>(W[0], W[1], W[2], W[3], W[4], wbf);

  for (int g = 0; g < 4; ++g)
    gemm_256<u16><<<256, 512, 131072, stream>>>(
        xbf + (size_t)g * GATE_ELEMS, wbf + (size_t)g * W_ELEMS, bias[g], gp[g]);

  scan_pass1<<<256, 256, 0, stream>>>(gp[0], gp[1], gp[2], Pbuf, clbuf);
  scan_pass2<<<16, 256, 0, stream>>>(Pbuf, clbuf, c0, cinbuf, out + GATE_ELEMS);
  scan_pass3<<<256, 256, 0, stream>>>(gp[0], gp[1], gp[2], gp[3], cinbuf, h,
                                      out + GATE_ELEMS + 4096);

  gemm_256<float><<<256, 512, 131072, stream>>>(h, wbf + 4 * W_ELEMS, bias[4], out);
}